// Round 9
// baseline (3668.211 us; speedup 1.0000x reference)
//
#include <hip/hip_runtime.h>
#include <math.h>

#define Bsz 256
#define Tsz 192
#define Fc 8
#define E0c 32
#define E1c 16
#define Hc 512
#define G4 2048
#define DINP 64
#define K1t 576    // 64 + 512
#define K2t 1024   // 512 + 512
#define NBLK 256
#define LBLK 32    // blocks per (group, layer)
#define KPAD1 584  // 576+8 ushorts (16B-aligned rows)
#define KPAD2 1032 // 1024+8 ushorts
#define LDSB_BYTES (64 * KPAD2 * 2)   // 132096
#define SLOT_STRIDE 16                // uints; 64 B per slot

typedef __attribute__((ext_vector_type(8))) short short8;
typedef __attribute__((ext_vector_type(4))) float f32x4;

static __device__ __forceinline__ float bf2f(ushort u) {
    return __uint_as_float(((uint)u) << 16);
}
static __device__ __forceinline__ ushort f2bf(float f) {
    uint u = __float_as_uint(f);
    u = (u + 0x7fffu + ((u >> 16) & 1u)) >> 16;
    return (ushort)u;
}

// ---------- build padded bf16 x, time-major [T][B][64] ----------
__global__ __launch_bounds__(256) void build_x_kernel(
    const float* __restrict__ x_cont, const int* __restrict__ cat0,
    const int* __restrict__ cat1, const float* __restrict__ emb0,
    const float* __restrict__ emb1, ushort* __restrict__ x_bf)
{
    int idx = blockIdx.x * 256 + threadIdx.x;
    if (idx >= Tsz * Bsz * DINP) return;
    int d = idx & 63;
    int row = idx >> 6;          // t*B + b
    int t = row >> 8;
    int b = row & 255;
    float v = 0.f;
    if (d < Fc)                  v = x_cont[(b * Tsz + t) * Fc + d];
    else if (d < Fc + E0c)       v = emb0[cat0[b * Tsz + t] * E0c + (d - Fc)];
    else if (d < Fc + E0c + E1c) v = emb1[cat1[b * Tsz + t] * E1c + (d - Fc - E0c)];
    x_bf[idx] = f2bf(v);
}

// ---------- transpose fp32 [K][2048] -> bf16 out[n][coff + k], row stride ldout ----------
__global__ __launch_bounds__(256) void transpose_w_kernel(
    const float* __restrict__ in, ushort* __restrict__ out, int K, int ldout, int coff)
{
    __shared__ float tile[32][33];
    int k0 = blockIdx.x * 32;
    int n0 = blockIdx.y * 32;
    int tx = threadIdx.x & 31, ty = threadIdx.x >> 5;
    #pragma unroll
    for (int p = 0; p < 4; ++p) {
        int k = k0 + ty + p * 8;
        tile[ty + p * 8][tx] = (k < K) ? in[k * G4 + n0 + tx] : 0.f;
    }
    __syncthreads();
    #pragma unroll
    for (int p = 0; p < 4; ++p) {
        int nl = ty + p * 8;
        out[(size_t)(n0 + nl) * ldout + coff + k0 + tx] = f2bf(tile[tx][nl]);
    }
}

// ---------- dual slot-array wait: RELAXED polls (no per-poll L2 invalidate) ----------
// lanes 0..31 poll a[]>=ta, lanes 32..63 poll b[]>=tb. Trailing __syncthreads.
static __device__ __forceinline__ void wait2(const uint* a, uint ta, const uint* b, uint tb) {
    int tid = threadIdx.x;
    if (tid < 64) {
        const uint* p = (tid < 32) ? (a + (tid & 31) * SLOT_STRIDE)
                                   : (b + (tid & 31) * SLOT_STRIDE);
        uint tg = (tid < 32) ? ta : tb;
        while (true) {
            uint v = __hip_atomic_load(p, __ATOMIC_RELAXED, __HIP_MEMORY_SCOPE_AGENT);
            if (__all((int)(v >= tg))) break;
            __builtin_amdgcn_s_sleep(1);
        }
    }
    __syncthreads();
}

// ---------- one layer's persistent loop ----------
// Group: 64 batch rows, 32 blocks per layer. Block: 64 rows x 64 z-cols
// (4 gates x 16 h-cols). Wave wv: rows m0+wv*16, all 4 gates.
// Weights in LDS (once). A burst-loaded each step (all loads in flight).
template<int KS_IN, int KS_TOT, int LDA_IN, int KPADv>
static __device__ __forceinline__ void run_layer(
    const ushort* __restrict__ Ain,    // [T][B][LDA_IN]
    ushort* __restrict__ hbuf,         // [T][B][512] own h
    const ushort* __restrict__ hz,     // [B][512] zeros
    const ushort* __restrict__ Wt,     // [2048][KS_TOT*32] bf16
    const float* __restrict__ bias,
    ushort* B_lds,
    const uint* dep_slots, uint dep_off,
    uint* own_slots, uint* my_slot,
    int m0, int j0)
{
    constexpr int KL = KS_TOT * 32;
    constexpr int SEGS = KL / 8;
    int tid = threadIdx.x;
    int lane = tid & 63, wv = tid >> 6;
    int lane15 = lane & 15, quad = lane >> 4;

    // ---- weights -> LDS once: LDS row = gate*16 + hcol ----
    for (int i = tid; i < 64 * SEGS; i += 256) {
        int row = i / SEGS, seg = i - row * SEGS;
        int gz = (row >> 4) * Hc + j0 + (row & 15);
        *(uint4*)&B_lds[row * KPADv + seg * 8] =
            *(const uint4*)(Wt + (size_t)gz * KL + seg * 8);
    }
    __syncthreads();

    float bgate[4];
    #pragma unroll
    for (int gt = 0; gt < 4; ++gt) bgate[gt] = bias[gt * Hc + j0 + lane15];
    float cst[4] = {0.f, 0.f, 0.f, 0.f};

    int arow = m0 + wv * 16 + lane15;    // A-fragment row for this lane
    int crow0 = m0 + wv * 16 + quad * 4; // epilogue batch-row base

    for (int t = 0; t < Tsz; ++t) {
        wait2(dep_slots, (uint)t + dep_off, own_slots, (uint)t);
        // one acquire per step (all waves): makes remote h/x stores visible
        __builtin_amdgcn_fence(__ATOMIC_ACQUIRE, "agent");

        const ushort* A0 = Ain + (size_t)t * Bsz * LDA_IN;
        const ushort* A1 = (t > 0) ? (hbuf + (size_t)(t - 1) * Bsz * Hc) : hz;

        // burst: issue ALL A-fragment loads, then fence the compiler so they
        // cannot sink into the MFMA loop (keeps KS_TOT loads in flight)
        uint4 areg[KS_TOT];
        {
            const ushort* p0 = A0 + (size_t)arow * LDA_IN + quad * 8;
            #pragma unroll
            for (int ks = 0; ks < KS_IN; ++ks)
                areg[ks] = *(const uint4*)(p0 + ks * 32);
            const ushort* p1 = A1 + (size_t)arow * Hc + quad * 8;
            #pragma unroll
            for (int ks = 0; ks < KS_TOT - KS_IN; ++ks)
                areg[KS_IN + ks] = *(const uint4*)(p1 + ks * 32);
        }
        asm volatile("" ::: "memory");

        f32x4 acc[4];
        #pragma unroll
        for (int gt = 0; gt < 4; ++gt) acc[gt] = (f32x4){0.f, 0.f, 0.f, 0.f};

        #pragma unroll
        for (int ks = 0; ks < KS_TOT; ++ks) {
            short8 av = __builtin_bit_cast(short8, areg[ks]);
            #pragma unroll
            for (int gt = 0; gt < 4; ++gt) {
                short8 bfr = *(const short8*)&B_lds[(gt * 16 + lane15) * KPADv + ks * 32 + quad * 8];
                acc[gt] = __builtin_amdgcn_mfma_f32_16x16x32_bf16(av, bfr, acc[gt], 0, 0, 0);
            }
        }

        // epilogue in-register: thread owns col j0+lane15, rows crow0+r
        #pragma unroll
        for (int r = 0; r < 4; ++r) {
            float zi = acc[0][r] + bgate[0];
            float zf = acc[1][r] + bgate[1];
            float zg = acc[2][r] + bgate[2];
            float zo = acc[3][r] + bgate[3];
            float ig = 1.f / (1.f + __expf(-zi));
            float fg = 1.f / (1.f + __expf(-zf));
            float gg = tanhf(zg);
            float og = 1.f / (1.f + __expf(-zo));
            float cn = fg * cst[r] + ig * gg;
            cst[r] = cn;
            float hn = og * tanhf(cn);
            __builtin_nontemporal_store(f2bf(hn),
                &hbuf[((size_t)t * Bsz + crow0 + r) * Hc + j0 + lane15]);
        }

        __syncthreads();   // all waves' h-stores drained (vmcnt0 before barrier)
        if (tid == 0)
            __hip_atomic_store(my_slot, (uint)(t + 1), __ATOMIC_RELEASE, __HIP_MEMORY_SCOPE_AGENT);
    }
}

// ---------- the persistent kernel ----------
// XCD-pinned mapping (assumes round-robin bid->XCD = bid&7):
//   xcd = bid&7; group g = xcd>>1 (64 batch rows, XCD pair {2g,2g+1});
//   role = xcd&1 (l1 on XCD 2g, l2 on XCD 2g+1); jb = bid>>3 (16 h-cols).
__global__ __launch_bounds__(256, 1) void deepar_persistent(
    const ushort* __restrict__ x_bf,
    const ushort* __restrict__ Wt1, const ushort* __restrict__ Wt2,
    const float* __restrict__ b1, const float* __restrict__ b2,
    ushort* __restrict__ h1, ushort* __restrict__ h2,
    const ushort* __restrict__ hz,
    const float* __restrict__ Wmu, const float* __restrict__ bmu,
    const float* __restrict__ Wsig, const float* __restrict__ bsig,
    float* __restrict__ out, uint* __restrict__ slots)
{
    extern __shared__ ushort B_lds[];

    int bid = blockIdx.x;
    int xcd = bid & 7;
    int g = xcd >> 1;
    int role = xcd & 1;
    int jb = bid >> 3;
    int m0 = g * 64;
    int j0 = jb * 16;
    uint* s_l1 = slots + (g * 2 + 0) * LBLK * SLOT_STRIDE;
    uint* s_l2 = slots + (g * 2 + 1) * LBLK * SLOT_STRIDE;

    if (role == 0) {
        run_layer<2, 18, DINP, KPAD1>(x_bf, h1, hz, Wt1, b1, B_lds,
                                      s_l1, 0u, s_l1, s_l1 + jb * SLOT_STRIDE, m0, j0);
        return;
    }
    run_layer<16, 32, Hc, KPAD2>(h1, h2, hz, Wt2, b2, B_lds,
                                 s_l1, 1u, s_l2, s_l2 + jb * SLOT_STRIDE, m0, j0);

    // ---- heads: group g's h2 fully published when all l2 slots hit Tsz ----
    wait2(s_l2, (uint)Tsz, s_l2, (uint)Tsz);
    __builtin_amdgcn_fence(__ATOMIC_ACQUIRE, "agent");

    int lane = threadIdx.x & 63, wv = threadIdx.x >> 6;
    float wm[8], wsg[8];
    #pragma unroll
    for (int i = 0; i < 8; ++i) {
        wm[i] = Wmu[lane * 8 + i];
        wsg[i] = Wsig[lane * 8 + i];
    }
    float bmu0 = bmu[0], bsg0 = bsig[0];
    for (int i = jb * 4 + wv; i < 64 * Tsz; i += 128) {
        int b = m0 + (i & 63);
        int t = i >> 6;
        const ushort* hp = h2 + ((size_t)t * Bsz + b) * Hc + lane * 8;
        short8 hv = *(const short8*)hp;
        float smu = 0.f, ssg = 0.f;
        #pragma unroll
        for (int e = 0; e < 8; ++e) {
            float f = bf2f((ushort)hv[e]);
            smu += f * wm[e];
            ssg += f * wsg[e];
        }
        #pragma unroll
        for (int off = 32; off > 0; off >>= 1) {
            smu += __shfl_down(smu, off, 64);
            ssg += __shfl_down(ssg, off, 64);
        }
        if (lane == 0) {
            int oi = b * Tsz + t;
            float sg = ssg + bsg0;
            float sp = sg > 0.f ? sg + log1pf(__expf(-sg)) : log1pf(__expf(sg));
            out[oi] = smu + bmu0;
            out[Bsz * Tsz + oi] = sp;
        }
    }
}

extern "C" void kernel_launch(void* const* d_in, const int* in_sizes, int n_in,
                              void* d_out, int out_size, void* d_ws, size_t ws_size,
                              hipStream_t stream) {
    const float* x_cont = (const float*)d_in[0];
    const int*   cat0   = (const int*)d_in[1];
    const int*   cat1   = (const int*)d_in[2];
    const float* emb0   = (const float*)d_in[3];
    const float* emb1   = (const float*)d_in[4];
    const float* Wk1    = (const float*)d_in[5];
    const float* Wr1    = (const float*)d_in[6];
    const float* b1     = (const float*)d_in[7];
    const float* Wk2    = (const float*)d_in[8];
    const float* Wr2    = (const float*)d_in[9];
    const float* b2     = (const float*)d_in[10];
    const float* Wmu    = (const float*)d_in[11];
    const float* bmu    = (const float*)d_in[12];
    const float* Wsig   = (const float*)d_in[13];
    const float* bsig   = (const float*)d_in[14];
    float* out = (float*)d_out;

    const size_t slots_bytes = 8 * LBLK * SLOT_STRIDE * 4;   // 16 KB

    char* ws = (char*)d_ws;
    uint*   slots = (uint*)ws;                                 ws += slots_bytes;
    ushort* x_bf  = (ushort*)ws;                               ws += (size_t)Tsz * Bsz * DINP * 2;
    ushort* Wt1   = (ushort*)ws;                               ws += (size_t)G4 * K1t * 2;
    ushort* Wt2   = (ushort*)ws;                               ws += (size_t)G4 * K2t * 2;
    ushort* h1    = (ushort*)ws;                               ws += (size_t)Tsz * Bsz * Hc * 2;
    ushort* h2    = (ushort*)ws;                               ws += (size_t)Tsz * Bsz * Hc * 2;
    ushort* hz    = (ushort*)ws;                               ws += (size_t)Bsz * Hc * 2;

    hipMemsetAsync(slots, 0, slots_bytes, stream);
    hipMemsetAsync(hz, 0, (size_t)Bsz * Hc * 2, stream);

    build_x_kernel<<<(Tsz * Bsz * DINP + 255) / 256, 256, 0, stream>>>(
        x_cont, cat0, cat1, emb0, emb1, x_bf);
    transpose_w_kernel<<<dim3(2, 64), 256, 0, stream>>>(Wk1, Wt1, 56, K1t, 0);
    transpose_w_kernel<<<dim3(16, 64), 256, 0, stream>>>(Wr1, Wt1, Hc, K1t, DINP);
    transpose_w_kernel<<<dim3(16, 64), 256, 0, stream>>>(Wk2, Wt2, Hc, K2t, 0);
    transpose_w_kernel<<<dim3(16, 64), 256, 0, stream>>>(Wr2, Wt2, Hc, K2t, Hc);

    hipFuncSetAttribute((const void*)deepar_persistent,
                        hipFuncAttributeMaxDynamicSharedMemorySize, LDSB_BYTES);
    deepar_persistent<<<dim3(NBLK), dim3(256), LDSB_BYTES, stream>>>(
        x_bf, Wt1, Wt2, b1, b2, h1, h2, hz, Wmu, bmu, Wsig, bsig, out, slots);
}

// Round 10
// 1429.345 us; speedup vs baseline: 2.5664x; 2.5664x over previous
//
#include <hip/hip_runtime.h>
#include <math.h>

#define Bsz 256
#define Tsz 192
#define Fc 8
#define E0c 32
#define E1c 16
#define Hc 512
#define G4 2048
#define DINP 64
#define K1t 576    // 64 + 512
#define K2t 1024   // 512 + 512
#define NBLK 256
#define LBLK 32    // blocks per (group, layer)
#define KPAD1 584  // 576+8 ushorts (16B-aligned rows)
#define KPAD2 1032 // 1024+8 ushorts
#define LDSB_BYTES (64 * KPAD2 * 2)   // 132096
#define SLOT_STRIDE 16                // uints; 64 B per slot

typedef __attribute__((ext_vector_type(8))) short short8;
typedef __attribute__((ext_vector_type(4))) float f32x4;

static __device__ __forceinline__ float bf2f(ushort u) {
    return __uint_as_float(((uint)u) << 16);
}
static __device__ __forceinline__ ushort f2bf(float f) {
    uint u = __float_as_uint(f);
    u = (u + 0x7fffu + ((u >> 16) & 1u)) >> 16;
    return (ushort)u;
}

// ---------- device-scope (sc1) primitives: no buffer_wbl2 / buffer_inv ----------
static __device__ __forceinline__ uint poll_sc1(const uint* p) {
    uint v;
    asm volatile("global_load_dword %0, %1, off sc1\n\t"
                 "s_waitcnt vmcnt(0)"
                 : "=v"(v) : "v"((unsigned long long)p) : "memory");
    return v;
}
static __device__ __forceinline__ void store_slot_sc1(uint* p, uint v) {
    asm volatile("global_store_dword %0, %1, off sc1"
                 :: "v"((unsigned long long)p), "v"(v) : "memory");
}

// ---------- build padded bf16 x, time-major [T][B][64] ----------
__global__ __launch_bounds__(256) void build_x_kernel(
    const float* __restrict__ x_cont, const int* __restrict__ cat0,
    const int* __restrict__ cat1, const float* __restrict__ emb0,
    const float* __restrict__ emb1, ushort* __restrict__ x_bf)
{
    int idx = blockIdx.x * 256 + threadIdx.x;
    if (idx >= Tsz * Bsz * DINP) return;
    int d = idx & 63;
    int row = idx >> 6;          // t*B + b
    int t = row >> 8;
    int b = row & 255;
    float v = 0.f;
    if (d < Fc)                  v = x_cont[(b * Tsz + t) * Fc + d];
    else if (d < Fc + E0c)       v = emb0[cat0[b * Tsz + t] * E0c + (d - Fc)];
    else if (d < Fc + E0c + E1c) v = emb1[cat1[b * Tsz + t] * E1c + (d - Fc - E0c)];
    x_bf[idx] = f2bf(v);
}

// ---------- transpose fp32 [K][2048] -> bf16 out[n][coff + k], row stride ldout ----------
__global__ __launch_bounds__(256) void transpose_w_kernel(
    const float* __restrict__ in, ushort* __restrict__ out, int K, int ldout, int coff)
{
    __shared__ float tile[32][33];
    int k0 = blockIdx.x * 32;
    int n0 = blockIdx.y * 32;
    int tx = threadIdx.x & 31, ty = threadIdx.x >> 5;
    #pragma unroll
    for (int p = 0; p < 4; ++p) {
        int k = k0 + ty + p * 8;
        tile[ty + p * 8][tx] = (k < K) ? in[k * G4 + n0 + tx] : 0.f;
    }
    __syncthreads();
    #pragma unroll
    for (int p = 0; p < 4; ++p) {
        int nl = ty + p * 8;
        out[(size_t)(n0 + nl) * ldout + coff + k0 + tx] = f2bf(tile[tx][nl]);
    }
}

// ---------- dual slot-array wait (sc1 polls) ----------
// lanes 0..31 poll a[]>=ta, lanes 32..63 poll b[]>=tb. Trailing __syncthreads.
static __device__ __forceinline__ void wait2(const uint* a, uint ta, const uint* b, uint tb) {
    int tid = threadIdx.x;
    if (tid < 64) {
        const uint* p = (tid < 32) ? (a + (tid & 31) * SLOT_STRIDE)
                                   : (b + (tid & 31) * SLOT_STRIDE);
        uint tg = (tid < 32) ? ta : tb;
        while (true) {
            uint v = poll_sc1(p);
            if (__all((int)(v >= tg))) break;
            __builtin_amdgcn_s_sleep(1);
        }
    }
    __syncthreads();
}

// ---------- one layer's persistent loop ----------
// Group: 64 batch rows, 32 blocks per layer. Block: 64 rows x 64 z-cols
// (4 gates x 16 h-cols). Wave wv: rows m0+wv*16, all 4 gates.
// Weights in LDS (once). A burst-loaded each step. All cross-block data
// (h, slots) moves via sc1 write-through stores -> L3; readers use normal
// cacheable loads (lines can never be stale: single write, read-after-slot).
template<int KS_IN, int KS_TOT, int LDA_IN, int KPADv>
static __device__ __forceinline__ void run_layer(
    const ushort* __restrict__ Ain,    // [T][B][LDA_IN]
    ushort* __restrict__ hbuf,         // [T][B][512] own h
    const ushort* __restrict__ hz,     // [B][512] zeros
    const ushort* __restrict__ Wt,     // [2048][KS_TOT*32] bf16
    const float* __restrict__ bias,
    ushort* B_lds,
    const uint* dep_slots, uint dep_off,
    uint* own_slots, uint* my_slot,
    int m0, int j0)
{
    constexpr int KL = KS_TOT * 32;
    constexpr int SEGS = KL / 8;
    int tid = threadIdx.x;
    int lane = tid & 63, wv = tid >> 6;
    int lane15 = lane & 15, quad = lane >> 4;

    // ---- weights -> LDS once: LDS row = gate*16 + hcol ----
    for (int i = tid; i < 64 * SEGS; i += 256) {
        int row = i / SEGS, seg = i - row * SEGS;
        int gz = (row >> 4) * Hc + j0 + (row & 15);
        *(uint4*)&B_lds[row * KPADv + seg * 8] =
            *(const uint4*)(Wt + (size_t)gz * KL + seg * 8);
    }
    __syncthreads();

    float bgate[4];
    #pragma unroll
    for (int gt = 0; gt < 4; ++gt) bgate[gt] = bias[gt * Hc + j0 + lane15];
    float cst[4] = {0.f, 0.f, 0.f, 0.f};

    int arow = m0 + wv * 16 + lane15;    // A-fragment row for this lane
    int crow0 = m0 + wv * 16 + quad * 4; // epilogue batch-row base

    for (int t = 0; t < Tsz; ++t) {
        wait2(dep_slots, (uint)t + dep_off, own_slots, (uint)t);

        const ushort* A0 = Ain + (size_t)t * Bsz * LDA_IN;
        const ushort* A1 = (t > 0) ? (hbuf + (size_t)(t - 1) * Bsz * Hc) : hz;

        // burst: issue ALL A-fragment loads, then compiler barrier so they
        // cannot sink into the MFMA loop
        uint4 areg[KS_TOT];
        {
            const ushort* p0 = A0 + (size_t)arow * LDA_IN + quad * 8;
            #pragma unroll
            for (int ks = 0; ks < KS_IN; ++ks)
                areg[ks] = *(const uint4*)(p0 + ks * 32);
            const ushort* p1 = A1 + (size_t)arow * Hc + quad * 8;
            #pragma unroll
            for (int ks = 0; ks < KS_TOT - KS_IN; ++ks)
                areg[KS_IN + ks] = *(const uint4*)(p1 + ks * 32);
        }
        asm volatile("" ::: "memory");

        f32x4 acc[4];
        #pragma unroll
        for (int gt = 0; gt < 4; ++gt) acc[gt] = (f32x4){0.f, 0.f, 0.f, 0.f};

        #pragma unroll
        for (int ks = 0; ks < KS_TOT; ++ks) {
            short8 av = __builtin_bit_cast(short8, areg[ks]);
            #pragma unroll
            for (int gt = 0; gt < 4; ++gt) {
                short8 bfr = *(const short8*)&B_lds[(gt * 16 + lane15) * KPADv + ks * 32 + quad * 8];
                acc[gt] = __builtin_amdgcn_mfma_f32_16x16x32_bf16(av, bfr, acc[gt], 0, 0, 0);
            }
        }

        // epilogue in-register: thread owns col j0+lane15, rows crow0..crow0+3
        uint hv[4];
        #pragma unroll
        for (int r = 0; r < 4; ++r) {
            float zi = acc[0][r] + bgate[0];
            float zf = acc[1][r] + bgate[1];
            float zg = acc[2][r] + bgate[2];
            float zo = acc[3][r] + bgate[3];
            float ig = 1.f / (1.f + __expf(-zi));
            float fg = 1.f / (1.f + __expf(-zf));
            float gg = tanhf(zg);
            float og = 1.f / (1.f + __expf(-zo));
            float cn = fg * cst[r] + ig * gg;
            cst[r] = cn;
            float hn = og * tanhf(cn);
            hv[r] = (uint)f2bf(hn);
        }
        // device-scope write-through stores (row stride = Hc*2 = 1024 B),
        // drained in-asm so the post-barrier slot store orders after them
        {
            unsigned long long hb = (unsigned long long)
                &hbuf[((size_t)t * Bsz + crow0) * Hc + j0 + lane15];
            asm volatile(
                "global_store_short %0, %1, off sc1\n\t"
                "global_store_short %0, %2, off offset:1024 sc1\n\t"
                "global_store_short %0, %3, off offset:2048 sc1\n\t"
                "global_store_short %0, %4, off offset:3072 sc1\n\t"
                "s_waitcnt vmcnt(0)"
                :: "v"(hb), "v"(hv[0]), "v"(hv[1]), "v"(hv[2]), "v"(hv[3])
                : "memory");
        }

        __syncthreads();   // all waves' sc1 h-stores complete (in L3)
        if (tid == 0)
            store_slot_sc1(my_slot, (uint)(t + 1));
    }
}

// ---------- the persistent kernel ----------
// XCD-pinned mapping (round-robin bid->XCD = bid&7):
//   xcd = bid&7; group g = xcd>>1; role = xcd&1 (l1 even XCD, l2 odd);
//   jb = bid>>3 (16 h-cols).
__global__ __launch_bounds__(256, 1) void deepar_persistent(
    const ushort* __restrict__ x_bf,
    const ushort* __restrict__ Wt1, const ushort* __restrict__ Wt2,
    const float* __restrict__ b1, const float* __restrict__ b2,
    ushort* __restrict__ h1, ushort* __restrict__ h2,
    const ushort* __restrict__ hz,
    const float* __restrict__ Wmu, const float* __restrict__ bmu,
    const float* __restrict__ Wsig, const float* __restrict__ bsig,
    float* __restrict__ out, uint* __restrict__ slots)
{
    extern __shared__ ushort B_lds[];

    int bid = blockIdx.x;
    int xcd = bid & 7;
    int g = xcd >> 1;
    int role = xcd & 1;
    int jb = bid >> 3;
    int m0 = g * 64;
    int j0 = jb * 16;
    uint* s_l1 = slots + (g * 2 + 0) * LBLK * SLOT_STRIDE;
    uint* s_l2 = slots + (g * 2 + 1) * LBLK * SLOT_STRIDE;

    if (role == 0) {
        run_layer<2, 18, DINP, KPAD1>(x_bf, h1, hz, Wt1, b1, B_lds,
                                      s_l1, 0u, s_l1, s_l1 + jb * SLOT_STRIDE, m0, j0);
        return;
    }
    run_layer<16, 32, Hc, KPAD2>(h1, h2, hz, Wt2, b2, B_lds,
                                 s_l1, 1u, s_l2, s_l2 + jb * SLOT_STRIDE, m0, j0);

    // ---- heads: group g's h2 fully published when all l2 slots hit Tsz ----
    wait2(s_l2, (uint)Tsz, s_l2, (uint)Tsz);

    int lane = threadIdx.x & 63, wv = threadIdx.x >> 6;
    float wm[8], wsg[8];
    #pragma unroll
    for (int i = 0; i < 8; ++i) {
        wm[i] = Wmu[lane * 8 + i];
        wsg[i] = Wsig[lane * 8 + i];
    }
    float bmu0 = bmu[0], bsg0 = bsig[0];
    for (int i = jb * 4 + wv; i < 64 * Tsz; i += 128) {
        int b = m0 + (i & 63);
        int t = i >> 6;
        const ushort* hp = h2 + ((size_t)t * Bsz + b) * Hc + lane * 8;
        short8 hvv = *(const short8*)hp;
        float smu = 0.f, ssg = 0.f;
        #pragma unroll
        for (int e = 0; e < 8; ++e) {
            float f = bf2f((ushort)hvv[e]);
            smu += f * wm[e];
            ssg += f * wsg[e];
        }
        #pragma unroll
        for (int off = 32; off > 0; off >>= 1) {
            smu += __shfl_down(smu, off, 64);
            ssg += __shfl_down(ssg, off, 64);
        }
        if (lane == 0) {
            int oi = b * Tsz + t;
            float sg = ssg + bsg0;
            float sp = sg > 0.f ? sg + log1pf(__expf(-sg)) : log1pf(__expf(sg));
            out[oi] = smu + bmu0;
            out[Bsz * Tsz + oi] = sp;
        }
    }
}

extern "C" void kernel_launch(void* const* d_in, const int* in_sizes, int n_in,
                              void* d_out, int out_size, void* d_ws, size_t ws_size,
                              hipStream_t stream) {
    const float* x_cont = (const float*)d_in[0];
    const int*   cat0   = (const int*)d_in[1];
    const int*   cat1   = (const int*)d_in[2];
    const float* emb0   = (const float*)d_in[3];
    const float* emb1   = (const float*)d_in[4];
    const float* Wk1    = (const float*)d_in[5];
    const float* Wr1    = (const float*)d_in[6];
    const float* b1     = (const float*)d_in[7];
    const float* Wk2    = (const float*)d_in[8];
    const float* Wr2    = (const float*)d_in[9];
    const float* b2     = (const float*)d_in[10];
    const float* Wmu    = (const float*)d_in[11];
    const float* bmu    = (const float*)d_in[12];
    const float* Wsig   = (const float*)d_in[13];
    const float* bsig   = (const float*)d_in[14];
    float* out = (float*)d_out;

    const size_t slots_bytes = 8 * LBLK * SLOT_STRIDE * 4;   // 16 KB

    char* ws = (char*)d_ws;
    uint*   slots = (uint*)ws;                                 ws += slots_bytes;
    ushort* x_bf  = (ushort*)ws;                               ws += (size_t)Tsz * Bsz * DINP * 2;
    ushort* Wt1   = (ushort*)ws;                               ws += (size_t)G4 * K1t * 2;
    ushort* Wt2   = (ushort*)ws;                               ws += (size_t)G4 * K2t * 2;
    ushort* h1    = (ushort*)ws;                               ws += (size_t)Tsz * Bsz * Hc * 2;
    ushort* h2    = (ushort*)ws;                               ws += (size_t)Tsz * Bsz * Hc * 2;
    ushort* hz    = (ushort*)ws;                               ws += (size_t)Bsz * Hc * 2;

    hipMemsetAsync(slots, 0, slots_bytes, stream);
    hipMemsetAsync(hz, 0, (size_t)Bsz * Hc * 2, stream);

    build_x_kernel<<<(Tsz * Bsz * DINP + 255) / 256, 256, 0, stream>>>(
        x_cont, cat0, cat1, emb0, emb1, x_bf);
    transpose_w_kernel<<<dim3(2, 64), 256, 0, stream>>>(Wk1, Wt1, 56, K1t, 0);
    transpose_w_kernel<<<dim3(16, 64), 256, 0, stream>>>(Wr1, Wt1, Hc, K1t, DINP);
    transpose_w_kernel<<<dim3(16, 64), 256, 0, stream>>>(Wk2, Wt2, Hc, K2t, 0);
    transpose_w_kernel<<<dim3(16, 64), 256, 0, stream>>>(Wr2, Wt2, Hc, K2t, Hc);

    hipFuncSetAttribute((const void*)deepar_persistent,
                        hipFuncAttributeMaxDynamicSharedMemorySize, LDSB_BYTES);
    deepar_persistent<<<dim3(NBLK), dim3(256), LDSB_BYTES, stream>>>(
        x_bf, Wt1, Wt2, b1, b2, h1, h2, hz, Wmu, bmu, Wsig, bsig, out, slots);
}

// Round 12
// 1363.933 us; speedup vs baseline: 2.6894x; 1.0480x over previous
//
#include <hip/hip_runtime.h>
#include <math.h>

#define Bsz 256
#define Tsz 192
#define Fc 8
#define E0c 32
#define E1c 16
#define Hc 512
#define G4 2048
#define DINP 64
#define K1t 576    // 64 + 512
#define K2t 1024   // 512 + 512
#define NBLK 256
#define LBLK 32    // blocks per (group, layer)
#define KPAD1 584  // 576+8 ushorts (16B-aligned rows)
#define KPAD2 1032 // 1024+8 ushorts
#define LDSB_BYTES (64 * KPAD2 * 2)   // 132096
#define SLOT_STRIDE 16                // uints; 64 B per slot

typedef __attribute__((ext_vector_type(8))) short short8;
typedef __attribute__((ext_vector_type(4))) float f32x4;

template<int N> struct IC { static constexpr int v = N; };
template<int C, int CMAX, typename F>
__device__ __forceinline__ void static_for(F&& f) {
    if constexpr (C < CMAX) {
        f(IC<C>{});
        static_for<C + 1, CMAX>(f);
    }
}

static __device__ __forceinline__ float bf2f(ushort u) {
    return __uint_as_float(((uint)u) << 16);
}
static __device__ __forceinline__ ushort f2bf(float f) {
    uint u = __float_as_uint(f);
    u = (u + 0x7fffu + ((u >> 16) & 1u)) >> 16;
    return (ushort)u;
}

// ---------- device-scope (sc1 = L3 coherence point) primitives ----------
// No buffer_wbl2 / buffer_inv anywhere in the steady-state loop.
static __device__ __forceinline__ uint poll_sc1(const uint* p) {
    uint v;
    asm volatile("global_load_dword %0, %1, off sc1\n\t"
                 "s_waitcnt vmcnt(0)"
                 : "=v"(v) : "v"((unsigned long long)p) : "memory");
    return v;
}
static __device__ __forceinline__ void store_slot_sc1(uint* p, uint v) {
    asm volatile("global_store_dword %0, %1, off sc1"
                 :: "v"((unsigned long long)p), "v"(v) : "memory");
}

// ---------- build padded bf16 x, time-major [T][B][64] ----------
__global__ __launch_bounds__(256) void build_x_kernel(
    const float* __restrict__ x_cont, const int* __restrict__ cat0,
    const int* __restrict__ cat1, const float* __restrict__ emb0,
    const float* __restrict__ emb1, ushort* __restrict__ x_bf)
{
    int idx = blockIdx.x * 256 + threadIdx.x;
    if (idx >= Tsz * Bsz * DINP) return;
    int d = idx & 63;
    int row = idx >> 6;          // t*B + b
    int t = row >> 8;
    int b = row & 255;
    float v = 0.f;
    if (d < Fc)                  v = x_cont[(b * Tsz + t) * Fc + d];
    else if (d < Fc + E0c)       v = emb0[cat0[b * Tsz + t] * E0c + (d - Fc)];
    else if (d < Fc + E0c + E1c) v = emb1[cat1[b * Tsz + t] * E1c + (d - Fc - E0c)];
    x_bf[idx] = f2bf(v);
}

// ---------- transpose fp32 [K][2048] -> bf16 out[n][coff + k], row stride ldout ----------
__global__ __launch_bounds__(256) void transpose_w_kernel(
    const float* __restrict__ in, ushort* __restrict__ out, int K, int ldout, int coff)
{
    __shared__ float tile[32][33];
    int k0 = blockIdx.x * 32;
    int n0 = blockIdx.y * 32;
    int tx = threadIdx.x & 31, ty = threadIdx.x >> 5;
    #pragma unroll
    for (int p = 0; p < 4; ++p) {
        int k = k0 + ty + p * 8;
        tile[ty + p * 8][tx] = (k < K) ? in[k * G4 + n0 + tx] : 0.f;
    }
    __syncthreads();
    #pragma unroll
    for (int p = 0; p < 4; ++p) {
        int nl = ty + p * 8;
        out[(size_t)(n0 + nl) * ldout + coff + k0 + tx] = f2bf(tile[tx][nl]);
    }
}

// ---------- slot-array wait: called by threads 0..63, 2 lanes/slot ----------
static __device__ __forceinline__ void wait_slots(const uint* arr, uint tg) {
    const uint* p = arr + (threadIdx.x & 31) * SLOT_STRIDE;
    while (true) {
        uint v = poll_sc1(p);
        if (__all((int)(v >= tg))) break;
        __builtin_amdgcn_s_sleep(1);
    }
}

// ---------- one layer's persistent loop ----------
// Group: 64 batch rows, 32 blocks per layer. Block: 64 rows x 64 z-cols
// (4 gates x 16 h-cols). Wave wv: rows m0+wv*16, all 4 gates.
// Weights in LDS (once). Two-phase step: phase A (dep-gated input half),
// phase B (own-gated recurrent half). All cross-block data via sc1 (L3).
template<int KS_IN, int KS_TOT, int LDA_IN, int KPADv, bool HAS_DEP>
static __device__ __forceinline__ void run_layer(
    const ushort* __restrict__ Ain,    // [T][B][LDA_IN]
    ushort* __restrict__ hbuf,         // [T][B][512] own h
    const ushort* __restrict__ hz,     // [B][512] zeros
    const ushort* __restrict__ Wt,     // [2048][KS_TOT*32] bf16
    const float* __restrict__ bias,
    ushort* B_lds,
    const uint* dep_slots,             // producer layer's slots (HAS_DEP only)
    uint* own_slots, uint* my_slot,
    int m0, int j0)
{
    constexpr int KS_R = KS_TOT - KS_IN;
    constexpr int KL = KS_TOT * 32;
    constexpr int SEGS = KL / 8;
    int tid = threadIdx.x;
    int lane = tid & 63, wv = tid >> 6;
    int lane15 = lane & 15, quad = lane >> 4;

    // ---- weights -> LDS once: LDS row = gate*16 + hcol ----
    for (int i = tid; i < 64 * SEGS; i += 256) {
        int row = i / SEGS, seg = i - row * SEGS;
        int gz = (row >> 4) * Hc + j0 + (row & 15);
        *(uint4*)&B_lds[row * KPADv + seg * 8] =
            *(const uint4*)(Wt + (size_t)gz * KL + seg * 8);
    }
    __syncthreads();

    float bgate[4];
    #pragma unroll
    for (int gt = 0; gt < 4; ++gt) bgate[gt] = bias[gt * Hc + j0 + lane15];
    float cst[4] = {0.f, 0.f, 0.f, 0.f};

    int arow = m0 + wv * 16 + lane15;    // A-fragment row for this lane
    int crow0 = m0 + wv * 16 + quad * 4; // epilogue batch-row base

    for (int t = 0; t < Tsz; ++t) {
        f32x4 acc[4];
        #pragma unroll
        for (int gt = 0; gt < 4; ++gt) acc[gt] = (f32x4){0.f, 0.f, 0.f, 0.f};

        // ======== phase A: input half (dep-gated) ========
        if constexpr (HAS_DEP) {
            if (tid < 64) wait_slots(dep_slots, (uint)(t + 1));  // producer done step t
            __syncthreads();
        }
        {
            const ushort* p0 = Ain + ((size_t)t * Bsz + arow) * LDA_IN + quad * 8;
            uint4 bufA[KS_IN];
            static_for<0, KS_IN>([&](auto Kc) {
                constexpr int ks = decltype(Kc)::v;
                bufA[ks] = *(const uint4*)(p0 + ks * 32);
            });
            asm volatile("" ::: "memory");
            static_for<0, KS_IN>([&](auto Kc) {
                constexpr int ks = decltype(Kc)::v;
                short8 av = __builtin_bit_cast(short8, bufA[ks]);
                #pragma unroll
                for (int gt = 0; gt < 4; ++gt) {
                    short8 bfr = *(const short8*)&B_lds[(gt * 16 + lane15) * KPADv + ks * 32 + quad * 8];
                    acc[gt] = __builtin_amdgcn_mfma_f32_16x16x32_bf16(av, bfr, acc[gt], 0, 0, 0);
                }
            });
        }

        // ======== phase B: recurrent half (own-gated) ========
        if (t) {
            if (tid < 64) wait_slots(own_slots, (uint)t);
            __syncthreads();
        }
        {
            const ushort* p1base = (t > 0) ? (hbuf + (size_t)(t - 1) * Bsz * Hc) : hz;
            const ushort* p1 = p1base + (size_t)arow * Hc + quad * 8;
            uint4 bufB[KS_R];
            static_for<0, KS_R>([&](auto Kc) {
                constexpr int ks = decltype(Kc)::v;
                bufB[ks] = *(const uint4*)(p1 + ks * 32);
            });
            asm volatile("" ::: "memory");
            static_for<0, KS_R>([&](auto Kc) {
                constexpr int ks = decltype(Kc)::v;
                short8 av = __builtin_bit_cast(short8, bufB[ks]);
                #pragma unroll
                for (int gt = 0; gt < 4; ++gt) {
                    short8 bfr = *(const short8*)&B_lds[(gt * 16 + lane15) * KPADv + (KS_IN + ks) * 32 + quad * 8];
                    acc[gt] = __builtin_amdgcn_mfma_f32_16x16x32_bf16(av, bfr, acc[gt], 0, 0, 0);
                }
            });
        }

        // ======== epilogue: thread owns col j0+lane15, rows crow0..crow0+3 ========
        uint hv[4];
        #pragma unroll
        for (int r = 0; r < 4; ++r) {
            float zi = acc[0][r] + bgate[0];
            float zf = acc[1][r] + bgate[1];
            float zg = acc[2][r] + bgate[2];
            float zo = acc[3][r] + bgate[3];
            float ig = 1.f / (1.f + __expf(-zi));
            float fg = 1.f / (1.f + __expf(-zf));
            float gg = tanhf(zg);
            float og = 1.f / (1.f + __expf(-zo));
            float cn = fg * cst[r] + ig * gg;
            cst[r] = cn;
            float hn = og * tanhf(cn);
            hv[r] = (uint)f2bf(hn);
        }
        {
            unsigned long long hb = (unsigned long long)
                &hbuf[((size_t)t * Bsz + crow0) * Hc + j0 + lane15];
            asm volatile(
                "global_store_short %0, %1, off sc1\n\t"
                "global_store_short %0, %2, off offset:1024 sc1\n\t"
                "global_store_short %0, %3, off offset:2048 sc1\n\t"
                "global_store_short %0, %4, off offset:3072 sc1\n\t"
                "s_waitcnt vmcnt(0)"
                :: "v"(hb), "v"(hv[0]), "v"(hv[1]), "v"(hv[2]), "v"(hv[3])
                : "memory");
        }

        __syncthreads();   // all waves' sc1 h-stores complete (at L3)
        if (tid == 0)
            store_slot_sc1(my_slot, (uint)(t + 1));
    }
}

// ---------- the persistent kernel ----------
// XCD mapping (bid&7) is a LOCALITY HEURISTIC ONLY — correctness relies solely
// on sc1 (L3) coherence for all cross-block data.
__global__ __launch_bounds__(256, 1) void deepar_persistent(
    const ushort* __restrict__ x_bf,
    const ushort* __restrict__ Wt1, const ushort* __restrict__ Wt2,
    const float* __restrict__ b1, const float* __restrict__ b2,
    ushort* __restrict__ h1, ushort* __restrict__ h2,
    const ushort* __restrict__ hz,
    const float* __restrict__ Wmu, const float* __restrict__ bmu,
    const float* __restrict__ Wsig, const float* __restrict__ bsig,
    float* __restrict__ out, uint* __restrict__ slots)
{
    extern __shared__ ushort B_lds[];

    int bid = blockIdx.x;
    int xcd = bid & 7;
    int g = xcd >> 1;
    int role = xcd & 1;
    int jb = bid >> 3;
    int m0 = g * 64;
    int j0 = jb * 16;
    uint* s_l1 = slots + (g * 2 + 0) * LBLK * SLOT_STRIDE;
    uint* s_l2 = slots + (g * 2 + 1) * LBLK * SLOT_STRIDE;

    if (role == 0) {
        run_layer<2, 18, DINP, KPAD1, false>(x_bf, h1, hz, Wt1, b1, B_lds,
                                             nullptr, s_l1, s_l1 + jb * SLOT_STRIDE, m0, j0);
        return;
    }
    run_layer<16, 32, Hc, KPAD2, true>(h1, h2, hz, Wt2, b2, B_lds,
                                       s_l1, s_l2, s_l2 + jb * SLOT_STRIDE, m0, j0);

    // ---- heads: group g's h2 fully published when all l2 slots hit Tsz ----
    if (threadIdx.x < 64) wait_slots(s_l2, (uint)Tsz);
    __syncthreads();

    int lane = threadIdx.x & 63, wv = threadIdx.x >> 6;
    float wm[8], wsg[8];
    #pragma unroll
    for (int i = 0; i < 8; ++i) {
        wm[i] = Wmu[lane * 8 + i];
        wsg[i] = Wsig[lane * 8 + i];
    }
    float bmu0 = bmu[0], bsg0 = bsig[0];
    for (int i = jb * 4 + wv; i < 64 * Tsz; i += 128) {
        int b = m0 + (i & 63);
        int t = i >> 6;
        const ushort* hp = h2 + ((size_t)t * Bsz + b) * Hc + lane * 8;
        short8 hvv = *(const short8*)hp;
        float smu = 0.f, ssg = 0.f;
        #pragma unroll
        for (int e = 0; e < 8; ++e) {
            float f = bf2f((ushort)hvv[e]);
            smu += f * wm[e];
            ssg += f * wsg[e];
        }
        #pragma unroll
        for (int off = 32; off > 0; off >>= 1) {
            smu += __shfl_down(smu, off, 64);
            ssg += __shfl_down(ssg, off, 64);
        }
        if (lane == 0) {
            int oi = b * Tsz + t;
            float sg = ssg + bsg0;
            float sp = sg > 0.f ? sg + log1pf(__expf(-sg)) : log1pf(__expf(sg));
            out[oi] = smu + bmu0;
            out[Bsz * Tsz + oi] = sp;
        }
    }
}

extern "C" void kernel_launch(void* const* d_in, const int* in_sizes, int n_in,
                              void* d_out, int out_size, void* d_ws, size_t ws_size,
                              hipStream_t stream) {
    const float* x_cont = (const float*)d_in[0];
    const int*   cat0   = (const int*)d_in[1];
    const int*   cat1   = (const int*)d_in[2];
    const float* emb0   = (const float*)d_in[3];
    const float* emb1   = (const float*)d_in[4];
    const float* Wk1    = (const float*)d_in[5];
    const float* Wr1    = (const float*)d_in[6];
    const float* b1     = (const float*)d_in[7];
    const float* Wk2    = (const float*)d_in[8];
    const float* Wr2    = (const float*)d_in[9];
    const float* b2     = (const float*)d_in[10];
    const float* Wmu    = (const float*)d_in[11];
    const float* bmu    = (const float*)d_in[12];
    const float* Wsig   = (const float*)d_in[13];
    const float* bsig   = (const float*)d_in[14];
    float* out = (float*)d_out;

    const size_t slots_bytes = 8 * LBLK * SLOT_STRIDE * 4;   // 16 KB

    char* ws = (char*)d_ws;
    uint*   slots = (uint*)ws;                                 ws += slots_bytes;
    ushort* x_bf  = (ushort*)ws;                               ws += (size_t)Tsz * Bsz * DINP * 2;
    ushort* Wt1   = (ushort*)ws;                               ws += (size_t)G4 * K1t * 2;
    ushort* Wt2   = (ushort*)ws;                               ws += (size_t)G4 * K2t * 2;
    ushort* h1    = (ushort*)ws;                               ws += (size_t)Tsz * Bsz * Hc * 2;
    ushort* h2    = (ushort*)ws;                               ws += (size_t)Tsz * Bsz * Hc * 2;
    ushort* hz    = (ushort*)ws;                               ws += (size_t)Bsz * Hc * 2;

    hipMemsetAsync(slots, 0, slots_bytes, stream);
    hipMemsetAsync(hz, 0, (size_t)Bsz * Hc * 2, stream);

    build_x_kernel<<<(Tsz * Bsz * DINP + 255) / 256, 256, 0, stream>>>(
        x_cont, cat0, cat1, emb0, emb1, x_bf);
    transpose_w_kernel<<<dim3(2, 64), 256, 0, stream>>>(Wk1, Wt1, 56, K1t, 0);
    transpose_w_kernel<<<dim3(16, 64), 256, 0, stream>>>(Wr1, Wt1, Hc, K1t, DINP);
    transpose_w_kernel<<<dim3(16, 64), 256, 0, stream>>>(Wk2, Wt2, Hc, K2t, 0);
    transpose_w_kernel<<<dim3(16, 64), 256, 0, stream>>>(Wr2, Wt2, Hc, K2t, Hc);

    hipFuncSetAttribute((const void*)deepar_persistent,
                        hipFuncAttributeMaxDynamicSharedMemorySize, LDSB_BYTES);
    deepar_persistent<<<dim3(NBLK), dim3(256), LDSB_BYTES, stream>>>(
        x_bf, Wt1, Wt2, b1, b2, h1, h2, hz, Wmu, bmu, Wsig, bsig, out, slots);
}